// Round 2
// baseline (204.730 us; speedup 1.0000x reference)
//
#include <hip/hip_runtime.h>

// ITA integer softmax, exact replica of the streaming group scan.
// x: (2,16,2048,2048) int32 in [-128,128) -> out uint8 values, stored as int32
// (harness reads the output buffer as int32 for this problem).
// Per row of K=2048: 128 groups of WIDTH=16; EPS_MAX = 32*8/256 = 1.0 exactly, so
// every float-round shift in the reference equals the integer difference.
// Exact reformulation:
//   P_g = prefix-max of group maxima (init -128), d_g = P_g - P_{g-1},
//   s_g = sum_k 256 >> min(P_g - x_k, 31)          (256>>s == 0 for s in [9,31])
//   eps = fold over g: eps = (eps >> min(d_g,31)) + s_g   (exact; eps < 2^20 so >>31==_rshift)
//   inv = 65280 / eps ; out_k = inv >> min(M - x_k, 31)    (M = row max, inv <= 255)

constexpr int K = 2048;
constexpr int SEG_STRIDE = 36;           // 32-word segments padded to 36 (144B, 16B aligned, bank-spread)
constexpr int ROW_LDS = SEG_STRIDE * (K / 32);   // 2304 words per row
constexpr int WAVES_PER_BLOCK = 4;

__global__ __launch_bounds__(256) void ita_softmax_kernel(
    const int* __restrict__ x, int* __restrict__ out, int nrows) {
  __shared__ int lds[WAVES_PER_BLOCK][ROW_LDS];
  const int lane = threadIdx.x & 63;
  const int wave = threadIdx.x >> 6;
  const int row = blockIdx.x * WAVES_PER_BLOCK + wave;
  const bool active = (row < nrows);
  int* myLds = lds[wave];

  // ---- Phase A: coalesced global -> padded LDS ----
  if (active) {
    const int* xr = x + (size_t)row * K;
#pragma unroll
    for (int j = 0; j < 8; ++j) {
      int4 v = *reinterpret_cast<const int4*>(xr + 256 * j + 4 * lane);
      // word w = 256j + 4*lane ; seg = 8j + (lane>>3) ; pos = 4*(lane&7)
      int addr = 288 * j + SEG_STRIDE * (lane >> 3) + 4 * (lane & 7);
      *reinterpret_cast<int4*>(myLds + addr) = v;
    }
  }
  __syncthreads();

  if (active) {
    // ---- Phase B: lane owns groups 2l, 2l+1 = words [32l, 32l+32) ----
    int xa[32];
#pragma unroll
    for (int k = 0; k < 8; ++k) {
      int4 v = *reinterpret_cast<const int4*>(myLds + SEG_STRIDE * lane + 4 * k);
      xa[4 * k + 0] = v.x; xa[4 * k + 1] = v.y;
      xa[4 * k + 2] = v.z; xa[4 * k + 3] = v.w;
    }
    int cmax0 = xa[0], cmax1 = xa[16];
#pragma unroll
    for (int i = 1; i < 16; ++i) {
      cmax0 = max(cmax0, xa[i]);
      cmax1 = max(cmax1, xa[16 + i]);
    }
    // inclusive prefix-max over lanes of this lane's pair-max
    int inc = max(cmax0, cmax1);
#pragma unroll
    for (int d = 1; d < 64; d <<= 1) {
      int t = __shfl_up(inc, d);
      if (lane >= d) inc = max(inc, t);
    }
    int E = __shfl_up(inc, 1);       // exclusive prefix-max (P_{2l-1})
    if (lane == 0) E = -128;         // reference init gmax
    const int P0 = max(E, cmax0);    // P_{2l}
    const int P1 = max(P0, cmax1);   // P_{2l+1}
    const int M = __shfl(inc, 63);   // row max

    int s0 = 0, s1 = 0;
#pragma unroll
    for (int i = 0; i < 16; ++i) {
      s0 += 256 >> min(P0 - xa[i], 31);        // diff>=9 -> 0; matches hw >=32 -> 0
      s1 += 256 >> min(P1 - xa[16 + i], 31);
    }
    // pack (d<<16 | s): d<=255, s<=4096 — both fit 16 bits
    const int pk0 = (int)(((unsigned)(P0 - E) << 16) | (unsigned)s0);
    const int pk1 = (int)(((unsigned)(P1 - P0) << 16) | (unsigned)s1);

    // ---- exact serial scan over 128 groups (wave-uniform) ----
    int eps = 0;
    for (int src = 0; src < 64; ++src) {
      unsigned a = (unsigned)__shfl(pk0, src);
      unsigned b = (unsigned)__shfl(pk1, src);
      eps = (eps >> min((int)(a >> 16), 31)) + (int)(a & 0xffffu);  // eps < 2^20 so >>31 == 0
      eps = (eps >> min((int)(b >> 16), 31)) + (int)(b & 0xffffu);
    }
    const int inv = 65280 / eps;  // eps >= 256 (max element contributes 256 and is never shifted after)

    // ---- Phase C: coalesced readback + int4 stores (output read as int32) ----
    int* orow = out + (size_t)row * K;
#pragma unroll
    for (int j = 0; j < 8; ++j) {
      int addr = 288 * j + SEG_STRIDE * (lane >> 3) + 4 * (lane & 7);
      int4 v = *reinterpret_cast<const int4*>(myLds + addr);
      int4 o;
      o.x = inv >> min(M - v.x, 31);  // inv <= 255 so shift>=9 -> 0; matches >=32 -> 0
      o.y = inv >> min(M - v.y, 31);
      o.z = inv >> min(M - v.z, 31);
      o.w = inv >> min(M - v.w, 31);
      *reinterpret_cast<int4*>(orow + 256 * j + 4 * lane) = o;
    }
  }
}

extern "C" void kernel_launch(void* const* d_in, const int* in_sizes, int n_in,
                              void* d_out, int out_size, void* d_ws, size_t ws_size,
                              hipStream_t stream) {
  const int* x = (const int*)d_in[0];
  int* out = (int*)d_out;
  const int nrows = in_sizes[0] / K;
  const int blocks = (nrows + WAVES_PER_BLOCK - 1) / WAVES_PER_BLOCK;
  ita_softmax_kernel<<<blocks, 256, 0, stream>>>(x, out, nrows);
}